// Round 6
// baseline (4872.981 us; speedup 1.0000x reference)
//
#include <hip/hip_runtime.h>

typedef _Float16 f16;
typedef _Float16 f16x2 __attribute__((ext_vector_type(2)));
typedef _Float16 f16x8 __attribute__((ext_vector_type(8)));
typedef _Float16 f16x4 __attribute__((ext_vector_type(4)));
typedef float f32x4 __attribute__((ext_vector_type(4)));

#define L2E 1.4426950408889634f
#define K2E 2.8853900817779268f

// ---- workspace layout (bytes)
#define O_PQV   0UL            // f32 [16384][512]  (aliased by GIH2C later)
#define O_GIH2C 0UL            // f16 [16384][1024]
#define O_CTX   33554432UL     // f16 [16384][256]; dead after gemms -> dec_h publish (8MB)
#define O_DEC   33554432UL     // dec_h: [512 t][2 half][512 units x 16B] = 8MB
#define O_ENCF  41943040UL     // f16 [16384][256]
#define O_GIH1  50331648UL     // f16 [16384][1024]; row (b*512+t) dead after L1 reads -> gx' in-place
#define O_WQV   92274688UL     // f16 [512][256]
#define O_W1    92536832UL     // f16 [1024][512]
#define O_W2    93585408UL     // f16 [1024][512]
#define O_WHH1  94633984UL     // f16 [1024][256]
#define O_WHH2  95158272UL     // f16 [1024][256]
#define O_BQV   95682560UL     // f32 [512]
#define O_B1    95684608UL     // f32 [1024]
#define O_B2    95688704UL     // f32 [1024]
#define O_V2    95692800UL     // f32 [256]  (= -2*V)
#define O_SUMV  95693824UL     // f32 [1]
#define O_FLG   95694848UL     // flag_dec[1024] ints @+0; flag_gx[1024] @+4096; memset 8KB
#define WS_NEED 95776768UL

__device__ __forceinline__ float fast_sigmoid(float x){
  float e = __builtin_amdgcn_exp2f(-L2E * x);
  return __builtin_amdgcn_rcpf(1.f + e);
}
__device__ __forceinline__ float fast_tanh(float x){
  float e = __builtin_amdgcn_exp2f(K2E * x);
  return 1.f - 2.f * __builtin_amdgcn_rcpf(1.f + e);
}

// 8B agent-scope atomic store (write-through to coherence point)
__device__ __forceinline__ void st8(void* p, unsigned long long v){
  __hip_atomic_store((unsigned long long*)p, v, __ATOMIC_RELAXED, __HIP_MEMORY_SCOPE_AGENT);
}
// cache-bypassing 16B load
template<int OFF>
__device__ __forceinline__ int4 ld_i4(const char* p){
  int4 r;
  asm volatile("global_load_dwordx4 %0, %1, off offset:%c2 sc0 sc1"
               : "=v"(r) : "v"(p), "i"(OFF) : "memory");
  return r;
}
// cache-bypassing flag load, completed in-asm
__device__ __forceinline__ int ld_flag(const int* p){
  int v;
  asm volatile("global_load_dword %0, %1, off sc0 sc1\n\ts_waitcnt vmcnt(0)"
               : "=v"(v) : "v"(p) : "memory");
  return v;
}

// ============ prep: weight conversions, biases =========
__global__ __launch_bounds__(256) void prep_kernel(
    const float* __restrict__ attn_W, const float* __restrict__ attn_b, const float* __restrict__ attn_V,
    const float* __restrict__ l1_Wih, const float* __restrict__ l1_Whh,
    const float* __restrict__ l1_bih, const float* __restrict__ l1_bhh,
    const float* __restrict__ l2_Wih, const float* __restrict__ l2_Whh,
    const float* __restrict__ l2_bih, const float* __restrict__ l2_bhh,
    const float* __restrict__ bcs, char* __restrict__ ws)
{
  long gid = (long)blockIdx.x*256 + threadIdx.x;
  if (gid < 131072){
    int j = (int)(gid >> 8), k = (int)(gid & 255);
    float v = (j < 256) ? attn_W[j*512 + k] : attn_W[(j-256)*512 + 256 + k];
    ((f16*)(ws+O_WQV))[gid] = (f16)(K2E * v);
    return;
  }
  gid -= 131072;
  if (gid < 524288){ ((f16*)(ws+O_W1))[gid] = (f16)l1_Wih[gid]; return; }
  gid -= 524288;
  if (gid < 524288){ ((f16*)(ws+O_W2))[gid] = (f16)l2_Wih[gid]; return; }
  gid -= 524288;
  if (gid < 262144){ ((f16*)(ws+O_WHH1))[gid] = (f16)l1_Whh[gid]; return; }
  gid -= 262144;
  if (gid < 262144){ ((f16*)(ws+O_WHH2))[gid] = (f16)l2_Whh[gid]; return; }
  gid -= 262144;
  if (gid < 512){ ((float*)(ws+O_BQV))[gid] = (gid < 256) ? 0.f : K2E*attn_b[gid-256]; return; }
  gid -= 512;
  if (gid < 1024){ ((float*)(ws+O_B1))[gid] = l1_bih[gid] + l1_bhh[gid]; return; }
  gid -= 1024;
  if (gid < 1024){ ((float*)(ws+O_B2))[gid] = l2_bih[gid] + l2_bhh[gid]; return; }
  gid -= 1024;
  if (gid < 256){ ((float*)(ws+O_V2))[gid] = -2.f*attn_V[gid]; return; }
  gid -= 256;
  if (gid == 0){
    float s = 0.f;
    for (int h=0; h<256; h++) s += attn_V[h];
    *((float*)(ws+O_SUMV)) = s;
  }
}

// ============ enc f32 -> f16 ============
__global__ __launch_bounds__(256) void encf_kernel(const float* __restrict__ enc, char* __restrict__ ws){
  f16* dst = (f16*)(ws + O_ENCF);
  int i = (blockIdx.x*256 + threadIdx.x)*4;
  float4 v = *(const float4*)(enc + i);
  f16x4 o; o[0] = (f16)v.x; o[1] = (f16)v.y; o[2] = (f16)v.z; o[3] = (f16)v.w;
  *(f16x4*)(dst + i) = o;
}

// ============ NT GEMM: C[M,N](f32|f16) = A[M,256(+256)] * B[N,K]^T + bias =========
template<bool CF16>
__global__ __launch_bounds__(256) void gemm_nt(const f16* __restrict__ A0, const f16* __restrict__ A1,
     int K0, const f16* __restrict__ B, int ldb, void* __restrict__ Cp, int ldc,
     int K, const float* __restrict__ bias)
{
  __shared__ f16 As[4096];
  __shared__ f16 Bs[4096];
  const int tid = threadIdx.x;
  const int lane = tid & 63;
  const int wave = tid >> 6;
  const int lm = lane & 15, kg = lane >> 4;
  const int mbase = blockIdx.y * 128;
  const int nbase = blockIdx.x * 128;
  const int wm = (wave >> 1) * 64, wn = (wave & 1) * 64;
  f32x4 acc[4][4];
#pragma unroll
  for (int i=0;i<4;i++)
#pragma unroll
    for (int j=0;j<4;j++) acc[i][j] = 0;
  const int r = tid >> 1, seg = tid & 1;
  for (int kc=0; kc<K; kc+=32){
    const f16* Ap = A0; int kk = kc;
    if (A1 && kc >= K0){ Ap = A1; kk = kc - K0; }
    {
      const f16* srcA = Ap + (size_t)(mbase + r)*256 + kk + seg*16;
      f16x8 va0 = *(const f16x8*)(srcA);
      f16x8 va1 = *(const f16x8*)(srcA + 8);
      *(f16x8*)&As[((seg*2+0)*128 + r)*8] = va0;
      *(f16x8*)&As[((seg*2+1)*128 + r)*8] = va1;
      const f16* srcB = B + (size_t)(nbase + r)*ldb + kc + seg*16;
      f16x8 vb0 = *(const f16x8*)(srcB);
      f16x8 vb1 = *(const f16x8*)(srcB + 8);
      *(f16x8*)&Bs[((seg*2+0)*128 + r)*8] = vb0;
      *(f16x8*)&Bs[((seg*2+1)*128 + r)*8] = vb1;
    }
    __syncthreads();
    f16x8 af[4], bfr[4];
#pragma unroll
    for (int i=0;i<4;i++) af[i]  = *(const f16x8*)&As[(kg*128 + wm + i*16 + lm)*8];
#pragma unroll
    for (int j=0;j<4;j++) bfr[j] = *(const f16x8*)&Bs[(kg*128 + wn + j*16 + lm)*8];
#pragma unroll
    for (int i=0;i<4;i++)
#pragma unroll
      for (int j=0;j<4;j++)
        acc[i][j] = __builtin_amdgcn_mfma_f32_16x16x32_f16(af[i], bfr[j], acc[i][j], 0,0,0);
    __syncthreads();
  }
#pragma unroll
  for (int i=0;i<4;i++){
#pragma unroll
    for (int j=0;j<4;j++){
      int col = nbase + wn + j*16 + lm;
      float bv = bias ? bias[col] : 0.f;
#pragma unroll
      for (int rr=0;rr<4;rr++){
        int row = mbase + wm + i*16 + kg*4 + rr;
        float v = acc[i][j][rr] + bv;
        if (CF16) ((f16*)Cp)[(size_t)row*ldc + col] = (f16)v;
        else      ((float*)Cp)[(size_t)row*ldc + col] = v;
      }
    }
  }
}

// ============ fused attention scores + softmax + ctx ============
__global__ __launch_bounds__(256) void score_ctx_kernel(char* __restrict__ ws,
     const float* __restrict__ enc, const int* __restrict__ inp_len)
{
  __shared__ float s_pq[8][260];
  __shared__ float s_pv[32][260];
  __shared__ float s_sc[8][512];
  __shared__ float s_v2[256];
  __shared__ float s_sv[1];
  const int tid = threadIdx.x;
  const int b = blockIdx.y;
  const int t0 = blockIdx.x * 8;
  const float* pqv = (const float*)(ws + O_PQV);
  f16* ctx = (f16*)(ws + O_CTX);
  const int len = inp_len[b];
  {
    int row = tid >> 5, cb = (tid & 31) * 8;
    const float* src = pqv + (size_t)(b*512 + t0 + row)*512 + cb;
    *(float4*)&s_pq[row][cb]   = *(const float4*)(src);
    *(float4*)&s_pq[row][cb+4] = *(const float4*)(src+4);
    s_v2[tid] = ((const float*)(ws + O_V2))[tid];
    if (tid == 0) s_sv[0] = *((const float*)(ws + O_SUMV));
  }
  const int tt = tid >> 5;
  const int ss2 = tid & 31;
  for (int st=0; st<16; st++){
    {
      int row = tid >> 3, cb = (tid & 7) * 32;
      const float* src = pqv + (size_t)(b*512 + st*32 + row)*512 + 256 + cb;
#pragma unroll
      for (int c=0;c<32;c+=4) *(float4*)&s_pv[row][cb+c] = *(const float4*)(src+c);
    }
    __syncthreads();
    float a0=0.f,a1=0.f,a2=0.f,a3=0.f;
#pragma unroll 8
    for (int h=0;h<256;h+=4){
      float4 q = *(const float4*)&s_pq[tt][h];
      float4 p = *(const float4*)&s_pv[ss2][h];
      float4 w = *(const float4*)&s_v2[h];
      float e0 = __builtin_amdgcn_exp2f(q.x+p.x);
      float e1 = __builtin_amdgcn_exp2f(q.y+p.y);
      float e2 = __builtin_amdgcn_exp2f(q.z+p.z);
      float e3 = __builtin_amdgcn_exp2f(q.w+p.w);
      a0 += w.x * __builtin_amdgcn_rcpf(1.f+e0);
      a1 += w.y * __builtin_amdgcn_rcpf(1.f+e1);
      a2 += w.z * __builtin_amdgcn_rcpf(1.f+e2);
      a3 += w.w * __builtin_amdgcn_rcpf(1.f+e3);
    }
    int s = st*32 + ss2;
    float sc = s_sv[0] + ((a0+a1)+(a2+a3));
    if (s >= len) sc = -1.0e9f;
    s_sc[tt][s] = sc;
    __syncthreads();
  }
  {
    float m = -3.0e38f;
#pragma unroll
    for (int k2=0;k2<16;k2++) m = fmaxf(m, s_sc[tt][ss2 + 32*k2]);
#pragma unroll
    for (int off=16; off>=1; off>>=1) m = fmaxf(m, __shfl_xor(m, off, 64));
    float sum = 0.f;
    float ebuf[16];
#pragma unroll
    for (int k2=0;k2<16;k2++){
      float e = __builtin_amdgcn_exp2f((s_sc[tt][ss2+32*k2] - m) * L2E);
      ebuf[k2] = e; sum += e;
    }
#pragma unroll
    for (int off=16; off>=1; off>>=1) sum += __shfl_xor(sum, off, 64);
    float rinv = __builtin_amdgcn_rcpf(sum);
#pragma unroll
    for (int k2=0;k2<16;k2++) s_sc[tt][ss2+32*k2] = ebuf[k2]*rinv;
  }
  __syncthreads();
  float acc[8] = {0,0,0,0,0,0,0,0};
  const int hg = tid & 31;
  for (int st=0; st<16; st++){
    {
      int row = tid >> 3, cb = (tid & 7)*32;
      const float* src = enc + (size_t)(b*512 + st*32 + row)*256 + cb;
#pragma unroll
      for (int c=0;c<32;c+=4) *(float4*)&s_pv[row][cb+c] = *(const float4*)(src+c);
    }
    __syncthreads();
#pragma unroll 4
    for (int si=0; si<32; si++){
      float a = s_sc[tt][st*32+si];
#pragma unroll
      for (int u=0;u<8;u++) acc[u] += a * s_pv[si][hg + 32*u];
    }
    __syncthreads();
  }
#pragma unroll
  for (int u=0;u<8;u++)
    ctx[(size_t)(b*512 + t0 + tt)*256 + hg + 32*u] = (f16)acc[u];
}

// ============ recurrences: 6-block pipeline, self-loops on-chip ============
// blocks 0,1 = L1 (batch halves): Whh1 resident; c in LDS A-buf, h in regs.
//   Wait-free. Publishes dec_h (8B agent atomics) + per-wave count-flag
//   (drain deferred one step -> no stall).
// blocks 2,3 = L1.5: W2x resident; polls dec flag, computes W2x@dec_h + gih2c,
//   publishes gate partials IN-PLACE into dead gih1[b,t] rows (f16, flag-gated).
// blocks 4,5 = L2: Whh2 resident; h2/c2 internal; polls gx flag (arrives ahead),
//   gx loads hidden under MFMA; writes out.
// Per block: 512 thr, 8 waves (2/SIMD, <=256 VGPR). Weights: 48 frags VGPR
// (K-chunks 2..7) + K-chunks 0,1 in LDS (128KB). MFMA M=16,N=1024,K=256.
// Gate-thread map: b = half*16 + (lane&15), k0 = wave*32 + (lane>>4)*8.
__global__ __launch_bounds__(512, 2) void rec_kernel(char* __restrict__ ws,
        const float* __restrict__ bhs, const float* __restrict__ bcs,
        const int* __restrict__ inp_len, float* __restrict__ out)
{
  __shared__ f16x8 lds_w[8192];        // 128KB: unit (kc*1024+col)*4+kg
  __shared__ float lds_gate[16][260];  // 16.3KB
  __shared__ f16x8 lds_a[512];         // 8KB: unit kc*64+lane (A fragments)
  const int tid = threadIdx.x;
  const int lane = tid & 63;
  const int wave = tid >> 6;
  const int lm = lane & 15;
  const int kg = lane >> 4;
  const int role = blockIdx.x >> 1;
  const int half = blockIdx.x & 1;
  const int bg = half*16 + lm;           // this thread's batch (gate phase)
  const int k0 = wave*32 + kg*8;         // this thread's k-slice base
  int* flag_dec = (int*)(ws + O_FLG);
  int* flag_gx  = (int*)(ws + O_FLG + 4096);
  f16* gih1  = (f16*)(ws + O_GIH1);
  const f16* gih2c = (const f16*)(ws + O_GIH2C);
  char* dec = ws + O_DEC;

  const f16* W; int ldw;
  if (role == 0)      { W = (const f16*)(ws + O_WHH1); ldw = 256; }
  else if (role == 1) { W = (const f16*)(ws + O_W2);   ldw = 512; } // dec-part cols k<256
  else                { W = (const f16*)(ws + O_WHH2); ldw = 256; }

  // stage K-chunks 0,1 of weights into LDS (one-time)
  for (int it = 0; it < 16; ++it){
    int g = it*512 + tid;
    int kc = g >> 12, rem = g & 4095, col = rem >> 2, kgi = rem & 3;
    lds_w[g] = *(const f16x8*)(W + (size_t)col*ldw + kc*32 + kgi*8);
  }
  // K-chunks 2..7 in VGPR: 48 fragments = 192 VGPR
  f16x8 bf[6][8];
#pragma unroll
  for (int kc = 0; kc < 6; ++kc)
#pragma unroll
    for (int n = 0; n < 8; ++n)
      bf[kc][n] = *(const f16x8*)(W + (size_t)(wave*128 + n*16 + lm)*ldw + (kc+2)*32 + kg*8);

  if (role == 0){
    f16x8 ci;
#pragma unroll
    for (int j = 0; j < 8; ++j) ci[j] = (f16)bcs[bg*256 + k0 + j];
    lds_a[wave*64 + lane] = ci;               // c(-1) = bcs
  } else if (role == 2){
    f16x8 z;
#pragma unroll
    for (int j = 0; j < 8; ++j) z[j] = (f16)0.f;
    lds_a[wave*64 + lane] = z;                // h2(-1) = 0
  }
  __syncthreads();

  if (role == 0){
    // ================= L1 (quirk: matmul uses c; c_new = f*h_prev + i*g~) ===
    float h[8];
#pragma unroll
    for (int j = 0; j < 8; ++j) h[j] = bhs[bg*256 + k0 + j];
    for (int t = 0; t < 512; ++t){
      const f16* gp = gih1 + ((size_t)(bg*512 + t))*1024 + k0;
      f16x8 gv0 = *(const f16x8*)(gp);
      f16x8 gv1 = *(const f16x8*)(gp + 256);
      f16x8 gv2 = *(const f16x8*)(gp + 512);
      f16x8 gv3 = *(const f16x8*)(gp + 768);
      f32x4 acc[8];
#pragma unroll
      for (int n = 0; n < 8; ++n) acc[n] = 0;
#pragma unroll
      for (int kc = 0; kc < 8; ++kc){
        f16x8 af = lds_a[kc*64 + lane];
#pragma unroll
        for (int n = 0; n < 8; ++n){
          f16x8 bw;
          if (kc < 2) bw = lds_w[(kc*1024 + wave*128 + n*16 + lm)*4 + kg];
          else        bw = bf[kc-2][n];
          acc[n] = __builtin_amdgcn_mfma_f32_16x16x32_f16(af, bw, acc[n], 0,0,0);
        }
      }
      // drain decp(t-1) stores (+ gih(t), needed now) then publish prev flag
      asm volatile("s_waitcnt vmcnt(0)" ::: "memory");
      __builtin_amdgcn_sched_barrier(0);
      if (t > 0 && lane == 0)
        __hip_atomic_fetch_add(flag_dec + (t-1)*2 + half, 1, __ATOMIC_RELAXED, __HIP_MEMORY_SCOPE_AGENT);
      // 4 gate rounds (r = i,f,g,o)
      float vi[8], vf[8], vg[8];
#pragma unroll
      for (int r = 0; r < 4; ++r){
        if ((wave >> 1) == r){
          int q = wave & 1;
#pragma unroll
          for (int n = 0; n < 8; ++n)
#pragma unroll
            for (int rr = 0; rr < 4; ++rr)
              lds_gate[kg*4 + rr][q*128 + n*16 + lm] = acc[n][rr];
        }
        __syncthreads();
        float ge[8];
        *(float4*)&ge[0] = *(float4*)&lds_gate[lm][k0];
        *(float4*)&ge[4] = *(float4*)&lds_gate[lm][k0+4];
        f16x8 gvr = (r==0) ? gv0 : (r==1) ? gv1 : (r==2) ? gv2 : gv3;
#pragma unroll
        for (int j = 0; j < 8; ++j){
          float pre = ge[j] + (float)gvr[j];
          if (r == 0) vi[j] = fast_sigmoid(pre);
          else if (r == 1) vf[j] = fast_sigmoid(pre);
          else if (r == 2) vg[j] = fast_tanh(pre);
          else {
            float vo = fast_sigmoid(pre);
            float cn = vf[j]*h[j] + vi[j]*vg[j];   // quirk
            float hn = vo*fast_tanh(cn);
            vg[j] = cn; vi[j] = hn;
          }
        }
        __syncthreads();
      }
      f16x8 cpk, hpk;
#pragma unroll
      for (int j = 0; j < 8; ++j){ cpk[j] = (f16)vg[j]; hpk[j] = (f16)vi[j]; h[j] = vi[j]; }
      lds_a[wave*64 + lane] = cpk;              // c(t) for next MFMA
      {
        char* dp = dec + ((size_t)(t*2 + half))*8192 + (size_t)(wave*64 + lane)*16;
        union { f16x8 v; unsigned long long u[2]; } pk; pk.v = hpk;
        st8(dp, pk.u[0]);
        st8(dp + 8, pk.u[1]);
      }
      __syncthreads();
    }
    asm volatile("s_waitcnt vmcnt(0)" ::: "memory");
    if (lane == 0)
      __hip_atomic_fetch_add(flag_dec + 511*2 + half, 1, __ATOMIC_RELAXED, __HIP_MEMORY_SCOPE_AGENT);

  } else if (role == 1){
    // ================= L1.5: gx' = W2x @ dec_h + gih2c, into dead gih1 rows ===
    for (int t = 0; t < 512; ++t){
      const int* fp = flag_dec + t*2 + half;
      while (ld_flag(fp) < 8) {}
      char* dp = dec + ((size_t)(t*2 + half))*8192 + (size_t)(wave*64 + lane)*16;
      int4 ar = ld_i4<0>(dp);
      const f16* gp = gih2c + ((size_t)(bg*512 + t))*1024 + k0;
      f16x8 gv0 = *(const f16x8*)(gp);
      f16x8 gv1 = *(const f16x8*)(gp + 256);
      f16x8 gv2 = *(const f16x8*)(gp + 512);
      f16x8 gv3 = *(const f16x8*)(gp + 768);
      asm volatile("s_waitcnt vmcnt(0)" ::: "memory");
      __builtin_amdgcn_sched_barrier(0);
      if (t > 0 && lane == 0)
        __hip_atomic_fetch_add(flag_gx + (t-1)*2 + half, 1, __ATOMIC_RELAXED, __HIP_MEMORY_SCOPE_AGENT);
      union { int4 i; f16x8 v; } au; au.i = ar;
      lds_a[wave*64 + lane] = au.v;
      __syncthreads();
      f32x4 acc[8];
#pragma unroll
      for (int n = 0; n < 8; ++n) acc[n] = 0;
#pragma unroll
      for (int kc = 0; kc < 8; ++kc){
        f16x8 af = lds_a[kc*64 + lane];
#pragma unroll
        for (int n = 0; n < 8; ++n){
          f16x8 bw;
          if (kc < 2) bw = lds_w[(kc*1024 + wave*128 + n*16 + lm)*4 + kg];
          else        bw = bf[kc-2][n];
          acc[n] = __builtin_amdgcn_mfma_f32_16x16x32_f16(af, bw, acc[n], 0,0,0);
        }
      }
#pragma unroll
      for (int r = 0; r < 4; ++r){
        if ((wave >> 1) == r){
          int q = wave & 1;
#pragma unroll
          for (int n = 0; n < 8; ++n)
#pragma unroll
            for (int rr = 0; rr < 4; ++rr)
              lds_gate[kg*4 + rr][q*128 + n*16 + lm] = acc[n][rr];
        }
        __syncthreads();
        float ge[8];
        *(float4*)&ge[0] = *(float4*)&lds_gate[lm][k0];
        *(float4*)&ge[4] = *(float4*)&lds_gate[lm][k0+4];
        f16x8 gvr = (r==0) ? gv0 : (r==1) ? gv1 : (r==2) ? gv2 : gv3;
        f16x8 opk;
#pragma unroll
        for (int j = 0; j < 8; ++j) opk[j] = (f16)(ge[j] + (float)gvr[j]);
        {
          f16* gxr = gih1 + ((size_t)(bg*512 + t))*1024 + r*256 + k0;
          union { f16x8 v; unsigned long long u[2]; } pk; pk.v = opk;
          st8(gxr, pk.u[0]);
          st8((char*)gxr + 8, pk.u[1]);
        }
        __syncthreads();
      }
    }
    asm volatile("s_waitcnt vmcnt(0)" ::: "memory");
    if (lane == 0)
      __hip_atomic_fetch_add(flag_gx + 511*2 + half, 1, __ATOMIC_RELAXED, __HIP_MEMORY_SCOPE_AGENT);

  } else {
    // ================= L2 (standard cell, masked freeze) ===
    float c2[8], hh[8];
#pragma unroll
    for (int j = 0; j < 8; ++j){ c2[j] = 0.f; hh[j] = 0.f; }
    const int lenv = inp_len[bg];
    for (int t = 0; t < 512; ++t){
      const int* fp = flag_gx + t*2 + half;
      while (ld_flag(fp) < 8) {}
      const char* grow = (const char*)(gih1 + ((size_t)(bg*512 + t))*1024 + k0);
      int4 g0 = ld_i4<0>(grow);
      int4 g1 = ld_i4<512>(grow);
      int4 g2 = ld_i4<1024>(grow);
      int4 g3 = ld_i4<1536>(grow);
      f32x4 acc[8];
#pragma unroll
      for (int n = 0; n < 8; ++n) acc[n] = 0;
#pragma unroll
      for (int kc = 0; kc < 8; ++kc){
        f16x8 af = lds_a[kc*64 + lane];
#pragma unroll
        for (int n = 0; n < 8; ++n){
          f16x8 bw;
          if (kc < 2) bw = lds_w[(kc*1024 + wave*128 + n*16 + lm)*4 + kg];
          else        bw = bf[kc-2][n];
          acc[n] = __builtin_amdgcn_mfma_f32_16x16x32_f16(af, bw, acc[n], 0,0,0);
        }
      }
      asm volatile("s_waitcnt vmcnt(0)" ::: "memory");   // gx arrived under MFMA
      __builtin_amdgcn_sched_barrier(0);
      union { int4 i; f16x8 v; } u0, u1, u2, u3;
      u0.i = g0; u1.i = g1; u2.i = g2; u3.i = g3;
      float vi[8], vf[8], vg[8], ov[8];
#pragma unroll
      for (int r = 0; r < 4; ++r){
        if ((wave >> 1) == r){
          int q = wave & 1;
#pragma unroll
          for (int n = 0; n < 8; ++n)
#pragma unroll
            for (int rr = 0; rr < 4; ++rr)
              lds_gate[kg*4 + rr][q*128 + n*16 + lm] = acc[n][rr];
        }
        __syncthreads();
        float ge[8];
        *(float4*)&ge[0] = *(float4*)&lds_gate[lm][k0];
        *(float4*)&ge[4] = *(float4*)&lds_gate[lm][k0+4];
        f16x8 gvr = (r==0) ? u0.v : (r==1) ? u1.v : (r==2) ? u2.v : u3.v;
#pragma unroll
        for (int j = 0; j < 8; ++j){
          float pre = ge[j] + (float)gvr[j];
          if (r == 0) vi[j] = fast_sigmoid(pre);
          else if (r == 1) vf[j] = fast_sigmoid(pre);
          else if (r == 2) vg[j] = fast_tanh(pre);
          else {
            float vo = fast_sigmoid(pre);
            float cn = vf[j]*c2[j] + vi[j]*vg[j];
            float hn = vo*fast_tanh(cn);
            bool valid = (t < lenv);
            c2[j] = valid ? cn : c2[j];
            hh[j] = valid ? hn : hh[j];
            ov[j] = valid ? hn : 0.f;
          }
        }
        __syncthreads();
      }
      f16x8 hpk;
#pragma unroll
      for (int j = 0; j < 8; ++j) hpk[j] = (f16)hh[j];
      lds_a[wave*64 + lane] = hpk;              // frozen h2(t) for next MFMA
      {
        float* op = out + ((size_t)(bg*512 + t))*256 + k0;
        float4 o0, o1;
        o0.x = ov[0]; o0.y = ov[1]; o0.z = ov[2]; o0.w = ov[3];
        o1.x = ov[4]; o1.y = ov[5]; o1.z = ov[6]; o1.w = ov[7];
        *(float4*)op = o0;
        *(float4*)(op + 4) = o1;
      }
      __syncthreads();
    }
  }
}

extern "C" void kernel_launch(void* const* d_in, const int* in_sizes, int n_in,
                              void* d_out, int out_size, void* d_ws, size_t ws_size,
                              hipStream_t stream) {
  if (ws_size < WS_NEED) return;  // workspace too small; bail (output stays poison -> visible failure)
  const float* enc    = (const float*)d_in[0];
  const float* bhs    = (const float*)d_in[1];
  const float* bcs    = (const float*)d_in[2];
  const float* attn_W = (const float*)d_in[3];
  const float* attn_b = (const float*)d_in[4];
  const float* attn_V = (const float*)d_in[5];
  const float* l1_Wih = (const float*)d_in[6];
  const float* l1_Whh = (const float*)d_in[7];
  const float* l1_bih = (const float*)d_in[8];
  const float* l1_bhh = (const float*)d_in[9];
  const float* l2_Wih = (const float*)d_in[10];
  const float* l2_Whh = (const float*)d_in[11];
  const float* l2_bih = (const float*)d_in[12];
  const float* l2_bhh = (const float*)d_in[13];
  const int* inp_len  = (const int*)d_in[14];
  char* ws = (char*)d_ws;
  float* out = (float*)d_out;

  prep_kernel<<<6700, 256, 0, stream>>>(attn_W, attn_b, attn_V, l1_Wih, l1_Whh, l1_bih, l1_bhh,
                                        l2_Wih, l2_Whh, l2_bih, l2_bhh, bcs, ws);
  encf_kernel<<<4096, 256, 0, stream>>>(enc, ws);
  // pqv = k2*(enc@Wq^T | enc@Wv^T + b)
  gemm_nt<false><<<dim3(4,128), 256, 0, stream>>>((const f16*)(ws+O_ENCF), nullptr, 256,
        (const f16*)(ws+O_WQV), 256, (void*)(ws+O_PQV), 512, 256, (const float*)(ws+O_BQV));
  score_ctx_kernel<<<dim3(64,32), 256, 0, stream>>>(ws, enc, inp_len);
  // gih1 = [enc|ctx]@W1^T + (bih1+bhh1)
  gemm_nt<true><<<dim3(8,128), 256, 0, stream>>>((const f16*)(ws+O_ENCF), (const f16*)(ws+O_CTX), 256,
        (const f16*)(ws+O_W1), 512, (void*)(ws+O_GIH1), 1024, 512, (const float*)(ws+O_B1));
  // gih2c = ctx@W2R^T + (bih2+bhh2)   (aliases pqv region; pqv dead after score_ctx)
  gemm_nt<true><<<dim3(8,128), 256, 0, stream>>>((const f16*)(ws+O_CTX), nullptr, 256,
        (const f16*)(ws+O_W2)+256, 512, (void*)(ws+O_GIH2C), 1024, 256, (const float*)(ws+O_B2));
  // zero protocol flags (dec/gx data regions are flag-gated, no memset needed)
  hipMemsetAsync(ws + O_FLG, 0, 8192UL, stream);
  rec_kernel<<<6, 512, 0, stream>>>(ws, bhs, bcs, inp_len, out);
}